// Round 4
// baseline (163.193 us; speedup 1.0000x reference)
//
#include <hip/hip_runtime.h>
#include <hip/hip_bf16.h>
#include <math.h>

// Problem dims (fixed by reference): B=64, N=32, S=1024, D=128
#define NB 64
#define NTOK 32
#define NS 1024
#define ND 128

typedef __attribute__((ext_vector_type(8))) short short8;  // 8 x bf16
typedef __attribute__((ext_vector_type(4))) float f32x4;

__device__ __forceinline__ unsigned short f2bf(float x) {
    unsigned int u = __builtin_bit_cast(unsigned int, x);
    u += 0x7fffu + ((u >> 16) & 1u);  // round-to-nearest-even
    return (unsigned short)(u >> 16);
}

// Fused convert, LDS-bounced so BOTH global sides are linear/coalesced.
// Tile = 16 rows x 128 cols fp32 -> fragment layout [tile][ks(4)][lane(64)][8].
// Map (identical to prior rounds): lane l holds row (l&15), k=ks*32+8*(l>>4)+j.
// 2 tiles per block. Thread t reads 32B linear per tile; its 8 elems are
// (row=t>>4, cols 8*(t&15)+j) -> slot ks=(t&15)>>2, lane=((t&3)<<4)|(t>>4).
__global__ __launch_bounds__(256) void convert_all(const float* __restrict__ q,
                                                   const float* __restrict__ dc,
                                                   const float* __restrict__ ng,
                                                   short* __restrict__ qf,
                                                   short* __restrict__ df,
                                                   short* __restrict__ nf) {
    __shared__ short lds[2][2048];
    int t = threadIdx.x;
    int row = t >> 4, g = t & 15;
    int slot = ((g >> 2) * 64 + (g & 3) * 16 + row);
#pragma unroll
    for (int half = 0; half < 2; ++half) {
        int tile = blockIdx.x * 2 + half;  // [0,128) q | [128,4224) doc | rest neg
        const float* in;
        int rel;
        if (tile < 128)       { in = q;  rel = tile; }
        else if (tile < 4224) { in = dc; rel = tile - 128; }
        else                  { in = ng; rel = tile - 4224; }
        const float4* src = (const float4*)(in + rel * 2048 + t * 8);
        float4 a = src[0], b = src[1];
        float f[8] = {a.x, a.y, a.z, a.w, b.x, b.y, b.z, b.w};
        short8 r;
#pragma unroll
        for (int j = 0; j < 8; ++j) r[j] = (short)f2bf(f[j]);
        *(short8*)(&lds[half][slot * 8]) = r;
    }
    __syncthreads();
#pragma unroll
    for (int half = 0; half < 2; ++half) {
        int tile = blockIdx.x * 2 + half;
        short* out;
        int rel;
        if (tile < 128)       { out = qf; rel = tile; }
        else if (tile < 4224) { out = df; rel = tile - 128; }
        else                  { out = nf; rel = tile - 4224; }
        *(short8*)(out + rel * 2048 + t * 8) = *(const short8*)(&lds[half][t * 8]);
    }
}

// Main in-batch maxsim + distributed neg partials.
// Grid (c=64, bg=8, sh=2) -> linear id = c + 64*bg + 512*sh -> XCD = c%8:
// all 16 blocks sharing a doc slice c are co-XCD (L2-hit after first fetch).
// 1024 blocks = 4 blocks/CU (VGPR<=128 via launch_bounds, LDS 32KB).
// Each block: s-half sh of doc[c] (8 chunks of 64 rows), per-wave 2 b's.
// Writes per-n rowmax partials score_part[sh][c][b][n]; sh==0 blocks also
// compute neg partial (b, s-chunk c) -> neg_part[c][b][n].
__global__ __launch_bounds__(256, 4) void maxsim_main(const short* __restrict__ qf,
                                                      const short* __restrict__ df,
                                                      const short* __restrict__ nf,
                                                      float* __restrict__ score_part,
                                                      float* __restrict__ neg_part) {
    int c = blockIdx.x;
    int bg = blockIdx.y;
    int sh = blockIdx.z;
    int t = threadIdx.x;
    int w = t >> 6, l = t & 63;
    int b0 = bg * 8 + w * 2;  // this wave: b0, b0+1

    __shared__ alignas(16) short lds[2][8192];  // 2 x 16KB chunks
    const short* dbase = df + c * (NS * ND) + sh * (8 * 8192);
    f32x4 zero = {0.f, 0.f, 0.f, 0.f};

    // issue chunk-0 loads immediately
    short8 ra[4], rb[4];
#pragma unroll
    for (int i = 0; i < 4; ++i)
        ra[i] = *(const short8*)(dbase + i * 2048 + t * 8);

    // q fragments: [bb][mtile][kstep] -> 64 VGPR
    short8 qa[2][2][4];
#pragma unroll
    for (int bb = 0; bb < 2; ++bb)
#pragma unroll
        for (int m = 0; m < 2; ++m)
#pragma unroll
            for (int ks = 0; ks < 4; ++ks)
                qa[bb][m][ks] =
                    *(const short8*)(qf + (((b0 + bb) * 2 + m) * 4 + ks) * 512 + l * 8);

    if (sh == 0) {  // fused neg partial: tile (b, s-chunk c) of q[b]·neg[b]
#pragma unroll
        for (int bb = 0; bb < 2; ++bb) {
            const short* nt_ = nf + (((b0 + bb) * 64 + c) * 4) * 512;
            short8 nb[4];
#pragma unroll
            for (int ks = 0; ks < 4; ++ks)
                nb[ks] = *(const short8*)(nt_ + ks * 512 + l * 8);
#pragma unroll
            for (int m = 0; m < 2; ++m) {
                f32x4 acc = zero;
#pragma unroll
                for (int ks = 0; ks < 4; ++ks)
                    acc = __builtin_amdgcn_mfma_f32_16x16x32_bf16(qa[bb][m][ks], nb[ks], acc, 0, 0, 0);
#pragma unroll
                for (int r = 0; r < 4; ++r) {  // rowmax over s within 16-lane group
                    float v = acc[r];
                    v = fmaxf(v, __shfl_xor(v, 1));
                    v = fmaxf(v, __shfl_xor(v, 2));
                    v = fmaxf(v, __shfl_xor(v, 4));
                    v = fmaxf(v, __shfl_xor(v, 8));
                    if ((l & 15) == 0)
                        neg_part[(c * 64 + (b0 + bb)) * 32 + m * 16 + (l >> 4) * 4 + r] = v;
                }
            }
        }
    }

    // write chunk0 (ra vmcnt covered by q/neg work), issue chunk1
#pragma unroll
    for (int i = 0; i < 4; ++i)
        *(short8*)(&lds[0][i * 2048 + t * 8]) = ra[i];
#pragma unroll
    for (int i = 0; i < 4; ++i)
        rb[i] = *(const short8*)(dbase + 8192 + i * 2048 + t * 8);
    __syncthreads();  // publish buf0

    f32x4 vmax[2][2];
#pragma unroll
    for (int bb = 0; bb < 2; ++bb)
#pragma unroll
        for (int m = 0; m < 2; ++m)
#pragma unroll
            for (int r = 0; r < 4; ++r) vmax[bb][m][r] = -INFINITY;

#define COMPUTE(PP)                                                                     \
    _Pragma("unroll") for (int ss = 0; ss < 4; ++ss) {                                  \
        short8 bf[4];                                                                   \
        _Pragma("unroll") for (int ks = 0; ks < 4; ++ks)                                \
            bf[ks] = *(const short8*)(&lds[PP][((ss * 4 + ks) * 64 + l) * 8]);          \
        _Pragma("unroll") for (int bb = 0; bb < 2; ++bb)                                \
            _Pragma("unroll") for (int m = 0; m < 2; ++m) {                             \
                f32x4 acc = zero;                                                       \
                _Pragma("unroll") for (int ks = 0; ks < 4; ++ks)                        \
                    acc = __builtin_amdgcn_mfma_f32_16x16x32_bf16(qa[bb][m][ks],        \
                                                                  bf[ks], acc, 0, 0, 0);\
                _Pragma("unroll") for (int r = 0; r < 4; ++r)                           \
                    vmax[bb][m][r] = fmaxf(vmax[bb][m][r], acc[r]);                     \
            }                                                                           \
    }

    // Invariant at loop top: buf0 = chunk ch (published), rb = chunk ch+1 (in flight)
    for (int it = 0; it < 4; ++it) {
        int ch = it * 2;
        if (ch + 2 < 8) {
#pragma unroll
            for (int i = 0; i < 4; ++i)
                ra[i] = *(const short8*)(dbase + (ch + 2) * 8192 + i * 2048 + t * 8);
        }
        COMPUTE(0);  // chunk ch
#pragma unroll
        for (int i = 0; i < 4; ++i)
            *(short8*)(&lds[1][i * 2048 + t * 8]) = rb[i];
        __syncthreads();  // publish buf1
        if (ch + 3 < 8) {
#pragma unroll
            for (int i = 0; i < 4; ++i)
                rb[i] = *(const short8*)(dbase + (ch + 3) * 8192 + i * 2048 + t * 8);
        }
        COMPUTE(1);  // chunk ch+1
        if (ch + 2 < 8) {
#pragma unroll
            for (int i = 0; i < 4; ++i)
                *(short8*)(&lds[0][i * 2048 + t * 8]) = ra[i];
            __syncthreads();  // publish buf0 for next iter (uniform branch)
        }
    }
#undef COMPUTE

    // per-n rowmax partial -> score_part[((sh*64 + c)*64 + b)*32 + n]
#pragma unroll
    for (int bb = 0; bb < 2; ++bb)
#pragma unroll
        for (int m = 0; m < 2; ++m)
#pragma unroll
            for (int r = 0; r < 4; ++r) {
                float v = vmax[bb][m][r];
                v = fmaxf(v, __shfl_xor(v, 1));
                v = fmaxf(v, __shfl_xor(v, 2));
                v = fmaxf(v, __shfl_xor(v, 4));
                v = fmaxf(v, __shfl_xor(v, 8));
                if ((l & 15) == 0)
                    score_part[((sh * 64 + c) * 64 + (b0 + bb)) * 32 + m * 16 + (l >> 4) * 4 + r] = v;
            }
}

// Per-b reduction: combine sh-halves -> scores[b][c] (in regs, c = lane),
// reduce neg_part over c, then CE + softplus -> bloss[b]. 64 blocks x 64 thr.
__global__ __launch_bounds__(64) void reduce_b(const float* __restrict__ score_part,
                                               const float* __restrict__ neg_part,
                                               const int* __restrict__ offp,
                                               float* __restrict__ bloss) {
    int b = blockIdx.x;
    int c = threadIdx.x;  // one wave
    const float4* p0 = (const float4*)(score_part + (c * 64 + b) * 32);
    const float4* p1 = (const float4*)(score_part + 64 * 64 * 32 + (c * 64 + b) * 32);
    float s = 0.f;
#pragma unroll
    for (int j = 0; j < 8; ++j) {
        float4 a = p0[j], q = p1[j];
        s += fmaxf(a.x, q.x) + fmaxf(a.y, q.y) + fmaxf(a.z, q.z) + fmaxf(a.w, q.w);
    }
    // neg: elementwise max over c of neg_part[c][b][n], then sum over n
    float v[32];
    {
        const float4* np = (const float4*)(neg_part + (c * 64 + b) * 32);
#pragma unroll
        for (int j = 0; j < 8; ++j) {
            float4 a = np[j];
            v[j * 4] = a.x; v[j * 4 + 1] = a.y; v[j * 4 + 2] = a.z; v[j * 4 + 3] = a.w;
        }
    }
#pragma unroll
    for (int off = 1; off < 64; off <<= 1)
#pragma unroll
        for (int j = 0; j < 32; ++j) v[j] = fmaxf(v[j], __shfl_xor(v[j], off));
    float negs = 0.f;
#pragma unroll
    for (int j = 0; j < 32; ++j) negs += v[j];

    const float invT = 50.0f;
    float m = s;
#pragma unroll
    for (int off = 1; off < 64; off <<= 1) m = fmaxf(m, __shfl_xor(m, off));
    float e = expf((s - m) * invT);
#pragma unroll
    for (int off = 1; off < 64; off <<= 1) e += __shfl_xor(e, off);
    float lse = m * invT + logf(e);
    int label = offp[0] + b;
    label = label < 0 ? 0 : (label > 63 ? 63 : label);
    float slabel = __shfl(s, label);
    float pos = __shfl(s, b);
    if (c == 0) {
        float x = (negs - pos) * invT;
        float sp = fmaxf(x, 0.f) + log1pf(expf(-fabsf(x)));
        bloss[b] = sp + lse - slabel * invT;
    }
}

__global__ __launch_bounds__(64) void final_sum(const float* __restrict__ bloss,
                                                float* __restrict__ out) {
    float v = bloss[threadIdx.x];
#pragma unroll
    for (int off = 1; off < 64; off <<= 1) v += __shfl_xor(v, off);
    if (threadIdx.x == 0) out[0] = v * (0.5f / 64.f);
}

extern "C" void kernel_launch(void* const* d_in, const int* in_sizes, int n_in,
                              void* d_out, int out_size, void* d_ws, size_t ws_size,
                              hipStream_t stream) {
    const float* q = (const float*)d_in[0];
    const float* dc = (const float*)d_in[1];
    const float* ng = (const float*)d_in[2];
    const int* offp = (const int*)d_in[3];
    float* out = (float*)d_out;

    // ws: qf 512KB | df 16MB | nf 16MB | neg_part 512KB | score_part 1MB | bloss
    char* ws = (char*)d_ws;
    short* qf = (short*)(ws);
    short* df = (short*)(ws + 0x80000);
    short* nf = (short*)(ws + 0x1080000);
    float* neg_part = (float*)(ws + 0x2080000);
    float* score_part = (float*)(ws + 0x2100000);
    float* bloss = (float*)(ws + 0x2200000);
    if (ws_size < 0x2200200) return;

    convert_all<<<4160, 256, 0, stream>>>(q, dc, ng, qf, df, nf);
    maxsim_main<<<dim3(64, 8, 2), 256, 0, stream>>>(qf, df, nf, score_part, neg_part);
    reduce_b<<<64, 64, 0, stream>>>(score_part, neg_part, offp, bloss);
    final_sum<<<1, 64, 0, stream>>>(bloss, out);
}

// Round 5
// 62.807 us; speedup vs baseline: 2.5983x; 2.5983x over previous
//
#include <hip/hip_runtime.h>
#include <hip/hip_bf16.h>
#include <math.h>

// Problem dims (fixed by reference): B=64, N=32, S=1024, D=128
#define NB 64
#define NTOK 32
#define NS 1024
#define ND 128

typedef __attribute__((ext_vector_type(8))) short short8;  // 8 x bf16
typedef __attribute__((ext_vector_type(4))) float f32x4;

__device__ __forceinline__ unsigned short f2bf(float x) {
    unsigned int u = __builtin_bit_cast(unsigned int, x);
    u += 0x7fffu + ((u >> 16) & 1u);  // round-to-nearest-even
    return (unsigned short)(u >> 16);
}

// Fused convert, LDS-bounced so BOTH global sides are linear/coalesced.
// Tile = 16 rows x 128 cols fp32 -> fragment layout [tile][ks(4)][lane(64)][8].
// Map (identical to prior rounds): lane l holds row (l&15), k=ks*32+8*(l>>4)+j.
__global__ __launch_bounds__(256) void convert_all(const float* __restrict__ q,
                                                   const float* __restrict__ dc,
                                                   const float* __restrict__ ng,
                                                   short* __restrict__ qf,
                                                   short* __restrict__ df,
                                                   short* __restrict__ nf) {
    __shared__ short lds[2][2048];
    int t = threadIdx.x;
    int row = t >> 4, g = t & 15;
    int slot = ((g >> 2) * 64 + (g & 3) * 16 + row);
#pragma unroll
    for (int half = 0; half < 2; ++half) {
        int tile = blockIdx.x * 2 + half;  // [0,128) q | [128,4224) doc | rest neg
        const float* in;
        int rel;
        if (tile < 128)       { in = q;  rel = tile; }
        else if (tile < 4224) { in = dc; rel = tile - 128; }
        else                  { in = ng; rel = tile - 4224; }
        const float4* src = (const float4*)(in + rel * 2048 + t * 8);
        float4 a = src[0], b = src[1];
        float f[8] = {a.x, a.y, a.z, a.w, b.x, b.y, b.z, b.w};
        short8 r;
#pragma unroll
        for (int j = 0; j < 8; ++j) r[j] = (short)f2bf(f[j]);
        *(short8*)(&lds[half][slot * 8]) = r;
    }
    __syncthreads();
#pragma unroll
    for (int half = 0; half < 2; ++half) {
        int tile = blockIdx.x * 2 + half;
        short* out;
        int rel;
        if (tile < 128)       { out = qf; rel = tile; }
        else if (tile < 4224) { out = df; rel = tile - 128; }
        else                  { out = nf; rel = tile - 4224; }
        *(short8*)(out + rel * 2048 + t * 8) = *(const short8*)(&lds[half][t * 8]);
    }
}

// Main in-batch maxsim + distributed neg partials.
// Grid (c=64, bg=8, sh=2) -> linear id = c + 64*bg + 512*sh -> XCD = c%8:
// all 16 blocks sharing doc slice c are co-XCD (L2-hit after first fetch).
// 1024 blocks; VGPR=128 (launch_bounds min-waves=2 -> NO forced cap; round-4's
// (256,4) forced VGPR=64 and spilled 280MB to scratch) -> HW still fits
// 4 waves/SIMD so occupancy comes from the grid, not a register cap.
__global__ __launch_bounds__(256, 2) void maxsim_main(const short* __restrict__ qf,
                                                      const short* __restrict__ df,
                                                      const short* __restrict__ nf,
                                                      float* __restrict__ score_part,
                                                      float* __restrict__ neg_part) {
    int c = blockIdx.x;
    int bg = blockIdx.y;
    int sh = blockIdx.z;
    int t = threadIdx.x;
    int w = t >> 6, l = t & 63;
    int b0 = bg * 8 + w * 2;  // this wave: b0, b0+1

    __shared__ alignas(16) short lds[2][8192];  // 2 x 16KB chunks
    const short* dbase = df + c * (NS * ND) + sh * (8 * 8192);
    f32x4 zero = {0.f, 0.f, 0.f, 0.f};

    // issue chunk-0 loads immediately
    short8 ra[4], rb[4];
#pragma unroll
    for (int i = 0; i < 4; ++i)
        ra[i] = *(const short8*)(dbase + i * 2048 + t * 8);

    // q fragments: [bb][mtile][kstep] -> 64 VGPR
    short8 qa[2][2][4];
#pragma unroll
    for (int bb = 0; bb < 2; ++bb)
#pragma unroll
        for (int m = 0; m < 2; ++m)
#pragma unroll
            for (int ks = 0; ks < 4; ++ks)
                qa[bb][m][ks] =
                    *(const short8*)(qf + (((b0 + bb) * 2 + m) * 4 + ks) * 512 + l * 8);

    if (sh == 0) {  // fused neg partial: tile (b, s-chunk c) of q[b]·neg[b]
#pragma unroll
        for (int bb = 0; bb < 2; ++bb) {
            const short* nt_ = nf + (((b0 + bb) * 64 + c) * 4) * 512;
            short8 nb[4];
#pragma unroll
            for (int ks = 0; ks < 4; ++ks)
                nb[ks] = *(const short8*)(nt_ + ks * 512 + l * 8);
#pragma unroll
            for (int m = 0; m < 2; ++m) {
                f32x4 acc = zero;
#pragma unroll
                for (int ks = 0; ks < 4; ++ks)
                    acc = __builtin_amdgcn_mfma_f32_16x16x32_bf16(qa[bb][m][ks], nb[ks], acc, 0, 0, 0);
#pragma unroll
                for (int r = 0; r < 4; ++r) {  // rowmax over s within 16-lane group
                    float v = acc[r];
                    v = fmaxf(v, __shfl_xor(v, 1));
                    v = fmaxf(v, __shfl_xor(v, 2));
                    v = fmaxf(v, __shfl_xor(v, 4));
                    v = fmaxf(v, __shfl_xor(v, 8));
                    if ((l & 15) == 0)
                        neg_part[(c * 64 + (b0 + bb)) * 32 + m * 16 + (l >> 4) * 4 + r] = v;
                }
            }
        }
    }

    // write chunk0 (ra vmcnt covered by q/neg work), issue chunk1
#pragma unroll
    for (int i = 0; i < 4; ++i)
        *(short8*)(&lds[0][i * 2048 + t * 8]) = ra[i];
#pragma unroll
    for (int i = 0; i < 4; ++i)
        rb[i] = *(const short8*)(dbase + 8192 + i * 2048 + t * 8);
    __syncthreads();  // publish buf0

    f32x4 vmax[2][2];
#pragma unroll
    for (int bb = 0; bb < 2; ++bb)
#pragma unroll
        for (int m = 0; m < 2; ++m)
#pragma unroll
            for (int r = 0; r < 4; ++r) vmax[bb][m][r] = -INFINITY;

#define COMPUTE(PP)                                                                     \
    _Pragma("unroll") for (int ss = 0; ss < 4; ++ss) {                                  \
        short8 bf[4];                                                                   \
        _Pragma("unroll") for (int ks = 0; ks < 4; ++ks)                                \
            bf[ks] = *(const short8*)(&lds[PP][((ss * 4 + ks) * 64 + l) * 8]);          \
        _Pragma("unroll") for (int bb = 0; bb < 2; ++bb)                                \
            _Pragma("unroll") for (int m = 0; m < 2; ++m) {                             \
                f32x4 acc = zero;                                                       \
                _Pragma("unroll") for (int ks = 0; ks < 4; ++ks)                        \
                    acc = __builtin_amdgcn_mfma_f32_16x16x32_bf16(qa[bb][m][ks],        \
                                                                  bf[ks], acc, 0, 0, 0);\
                _Pragma("unroll") for (int r = 0; r < 4; ++r)                           \
                    vmax[bb][m][r] = fmaxf(vmax[bb][m][r], acc[r]);                     \
            }                                                                           \
    }

    // Invariant at loop top: buf0 = chunk ch (published), rb = chunk ch+1 (in flight)
    for (int it = 0; it < 4; ++it) {
        int ch = it * 2;
        if (ch + 2 < 8) {
#pragma unroll
            for (int i = 0; i < 4; ++i)
                ra[i] = *(const short8*)(dbase + (ch + 2) * 8192 + i * 2048 + t * 8);
        }
        COMPUTE(0);  // chunk ch
#pragma unroll
        for (int i = 0; i < 4; ++i)
            *(short8*)(&lds[1][i * 2048 + t * 8]) = rb[i];
        __syncthreads();  // publish buf1
        if (ch + 3 < 8) {
#pragma unroll
            for (int i = 0; i < 4; ++i)
                rb[i] = *(const short8*)(dbase + (ch + 3) * 8192 + i * 2048 + t * 8);
        }
        COMPUTE(1);  // chunk ch+1
        if (ch + 2 < 8) {
#pragma unroll
            for (int i = 0; i < 4; ++i)
                *(short8*)(&lds[0][i * 2048 + t * 8]) = ra[i];
            __syncthreads();  // publish buf0 for next iter (uniform branch)
        }
    }
#undef COMPUTE

    // per-n rowmax partial -> score_part[((sh*64 + c)*64 + b)*32 + n]
#pragma unroll
    for (int bb = 0; bb < 2; ++bb)
#pragma unroll
        for (int m = 0; m < 2; ++m)
#pragma unroll
            for (int r = 0; r < 4; ++r) {
                float v = vmax[bb][m][r];
                v = fmaxf(v, __shfl_xor(v, 1));
                v = fmaxf(v, __shfl_xor(v, 2));
                v = fmaxf(v, __shfl_xor(v, 4));
                v = fmaxf(v, __shfl_xor(v, 8));
                if ((l & 15) == 0)
                    score_part[((sh * 64 + c) * 64 + (b0 + bb)) * 32 + m * 16 + (l >> 4) * 4 + r] = v;
            }
}

// Per-b reduction: combine sh-halves -> scores[b][c] (in regs, c = lane),
// reduce neg_part over c, then CE + softplus -> bloss[b]. 64 blocks x 64 thr.
__global__ __launch_bounds__(64) void reduce_b(const float* __restrict__ score_part,
                                               const float* __restrict__ neg_part,
                                               const int* __restrict__ offp,
                                               float* __restrict__ bloss) {
    int b = blockIdx.x;
    int c = threadIdx.x;  // one wave
    const float4* p0 = (const float4*)(score_part + (c * 64 + b) * 32);
    const float4* p1 = (const float4*)(score_part + 64 * 64 * 32 + (c * 64 + b) * 32);
    float s = 0.f;
#pragma unroll
    for (int j = 0; j < 8; ++j) {
        float4 a = p0[j], q = p1[j];
        s += fmaxf(a.x, q.x) + fmaxf(a.y, q.y) + fmaxf(a.z, q.z) + fmaxf(a.w, q.w);
    }
    // neg: elementwise max over c of neg_part[c][b][n], then sum over n
    float v[32];
    {
        const float4* np = (const float4*)(neg_part + (c * 64 + b) * 32);
#pragma unroll
        for (int j = 0; j < 8; ++j) {
            float4 a = np[j];
            v[j * 4] = a.x; v[j * 4 + 1] = a.y; v[j * 4 + 2] = a.z; v[j * 4 + 3] = a.w;
        }
    }
#pragma unroll
    for (int off = 1; off < 64; off <<= 1)
#pragma unroll
        for (int j = 0; j < 32; ++j) v[j] = fmaxf(v[j], __shfl_xor(v[j], off));
    float negs = 0.f;
#pragma unroll
    for (int j = 0; j < 32; ++j) negs += v[j];

    const float invT = 50.0f;
    float m = s;
#pragma unroll
    for (int off = 1; off < 64; off <<= 1) m = fmaxf(m, __shfl_xor(m, off));
    float e = expf((s - m) * invT);
#pragma unroll
    for (int off = 1; off < 64; off <<= 1) e += __shfl_xor(e, off);
    float lse = m * invT + logf(e);
    int label = offp[0] + b;
    label = label < 0 ? 0 : (label > 63 ? 63 : label);
    float slabel = __shfl(s, label);
    float pos = __shfl(s, b);
    if (c == 0) {
        float x = (negs - pos) * invT;
        float sp = fmaxf(x, 0.f) + log1pf(expf(-fabsf(x)));
        bloss[b] = sp + lse - slabel * invT;
    }
}

__global__ __launch_bounds__(64) void final_sum(const float* __restrict__ bloss,
                                                float* __restrict__ out) {
    float v = bloss[threadIdx.x];
#pragma unroll
    for (int off = 1; off < 64; off <<= 1) v += __shfl_xor(v, off);
    if (threadIdx.x == 0) out[0] = v * (0.5f / 64.f);
}

extern "C" void kernel_launch(void* const* d_in, const int* in_sizes, int n_in,
                              void* d_out, int out_size, void* d_ws, size_t ws_size,
                              hipStream_t stream) {
    const float* q = (const float*)d_in[0];
    const float* dc = (const float*)d_in[1];
    const float* ng = (const float*)d_in[2];
    const int* offp = (const int*)d_in[3];
    float* out = (float*)d_out;

    // ws: qf 512KB | df 16MB | nf 16MB | neg_part 512KB | score_part 1MB | bloss
    char* ws = (char*)d_ws;
    short* qf = (short*)(ws);
    short* df = (short*)(ws + 0x80000);
    short* nf = (short*)(ws + 0x1080000);
    float* neg_part = (float*)(ws + 0x2080000);
    float* score_part = (float*)(ws + 0x2100000);
    float* bloss = (float*)(ws + 0x2200000);
    if (ws_size < 0x2200200) return;

    convert_all<<<4160, 256, 0, stream>>>(q, dc, ng, qf, df, nf);
    maxsim_main<<<dim3(64, 8, 2), 256, 0, stream>>>(qf, df, nf, score_part, neg_part);
    reduce_b<<<64, 64, 0, stream>>>(score_part, neg_part, offp, bloss);
    final_sum<<<1, 64, 0, stream>>>(bloss, out);
}